// Round 5
// baseline (223.675 us; speedup 1.0000x reference)
//
#include <hip/hip_runtime.h>
#include <math.h>

// Problem constants (from reference): w is [B, N] float32, L = 1.0
#define B_ROWS 16384
#define N_COLS 2048

// ---- ws layout (floats) ----
// Partials: 1024 rowchunks x 4096 floats ([0,2048)=colsum, [2048,4096)=colsum2)
#define WS_PART     0
#define WS_MEAN     (1024 * 4096)                // 2048
#define WS_INVSTD   (WS_MEAN + N_COLS)           // 2048
#define WS_RP       (WS_INVSTD + N_COLS)         // 4096 rowpass block partials
// total ~16.8 MB

// ---------------- Pass 1: per-rowchunk column partial sums ----------------
// 2048 blocks = 1024 rowchunks x 2 colgroups, 16 rows each.
// __launch_bounds__(256,8) forces VGPR<=64 -> 8 blocks/CU = 32 waves/CU.
// '#pragma unroll 1' keeps exactly ONE 8-deep load batch live (32 VGPRs),
// so the register allocator cannot merge both batches and blow the budget.
constexpr int K1_ROWCHUNKS = 1024;
constexpr int K1_ROWS = B_ROWS / K1_ROWCHUNKS;  // = 16

__global__ __launch_bounds__(256, 8) void colstats_kernel(
    const float* __restrict__ w, float* __restrict__ part) {
  const int cg = blockIdx.x & 1;
  const int rc = blockIdx.x >> 1;
  const int col4 = cg * 256 + threadIdx.x;  // float4 column index in [0,512)
  const float4* __restrict__ w4 = reinterpret_cast<const float4*>(w) + col4;
  const size_t stride = N_COLS / 4;
  const size_t base = (size_t)rc * K1_ROWS * stride;

  float sx = 0.f, sy = 0.f, sz = 0.f, sw = 0.f;
  float qx = 0.f, qy = 0.f, qz = 0.f, qw = 0.f;
#pragma unroll 1
  for (int batch = 0; batch < K1_ROWS / 8; ++batch) {
    float4 v[8];
#pragma unroll
    for (int i = 0; i < 8; ++i)
      v[i] = w4[base + (size_t)(batch * 8 + i) * stride];
#pragma unroll
    for (int i = 0; i < 8; ++i) {
      sx += v[i].x; sy += v[i].y; sz += v[i].z; sw += v[i].w;
      qx = fmaf(v[i].x, v[i].x, qx);
      qy = fmaf(v[i].y, v[i].y, qy);
      qz = fmaf(v[i].z, v[i].z, qz);
      qw = fmaf(v[i].w, v[i].w, qw);
    }
  }
  float4* __restrict__ p4 = reinterpret_cast<float4*>(part);
  p4[(size_t)rc * 1024 + col4] = make_float4(sx, sy, sz, sw);
  p4[(size_t)rc * 1024 + 512 + col4] = make_float4(qx, qy, qz, qw);
}

// ---------------- Fused reduce (1024 chunks) + finalize mean/invstd ----------------
// 128 blocks x 256 threads. Thread: c4 = blk*4 + (tid&3), chunk-sub = tid>>2
// (64-way split, 16 chunks each). Wave shuffle reduces 16 subs; LDS combines
// the 4 waves; 4 threads/block finalize 16 columns.
__global__ __launch_bounds__(256) void stats_reduce_kernel(
    const float* __restrict__ part, float* __restrict__ ws) {
  const int tid = threadIdx.x;
  const int c4 = blockIdx.x * 4 + (tid & 3);  // float4 column index
  const int sub = tid >> 2;                   // 0..63
  const float4* __restrict__ p4 = reinterpret_cast<const float4*>(part);

  float4 s = make_float4(0.f, 0.f, 0.f, 0.f);
  float4 q = make_float4(0.f, 0.f, 0.f, 0.f);
#pragma unroll 1
  for (int i = 0; i < 16; ++i) {
    const int rc = sub * 16 + i;
    float4 a = p4[(size_t)rc * 1024 + c4];
    float4 b = p4[(size_t)rc * 1024 + 512 + c4];
    s.x += a.x; s.y += a.y; s.z += a.z; s.w += a.w;
    q.x += b.x; q.y += b.y; q.z += b.z; q.w += b.w;
  }
  // Reduce over sub bits within the wave (sub bits 0..3 = lane bits 2..5).
#pragma unroll
  for (int off = 4; off <= 32; off <<= 1) {
    s.x += __shfl_xor(s.x, off); s.y += __shfl_xor(s.y, off);
    s.z += __shfl_xor(s.z, off); s.w += __shfl_xor(s.w, off);
    q.x += __shfl_xor(q.x, off); q.y += __shfl_xor(q.y, off);
    q.z += __shfl_xor(q.z, off); q.w += __shfl_xor(q.w, off);
  }
  __shared__ float4 red_s[4][4];  // [wave][c4 residue]
  __shared__ float4 red_q[4][4];
  const int wid = tid >> 6;
  const int lane = tid & 63;
  if (lane < 4) {
    red_s[wid][lane] = s;
    red_q[wid][lane] = q;
  }
  __syncthreads();
  if (tid < 4) {
    float4 S = red_s[0][tid], Q = red_q[0][tid];
#pragma unroll
    for (int w_ = 1; w_ < 4; ++w_) {
      S.x += red_s[w_][tid].x; S.y += red_s[w_][tid].y;
      S.z += red_s[w_][tid].z; S.w += red_s[w_][tid].w;
      Q.x += red_q[w_][tid].x; Q.y += red_q[w_][tid].y;
      Q.z += red_q[w_][tid].z; Q.w += red_q[w_][tid].w;
    }
    const float inv_b = 1.0f / (float)B_ROWS;
    float4 mean, inv;
    mean.x = S.x * inv_b; mean.y = S.y * inv_b;
    mean.z = S.z * inv_b; mean.w = S.w * inv_b;
    inv.x = 1.0f / sqrtf(Q.x * inv_b - mean.x * mean.x);
    inv.y = 1.0f / sqrtf(Q.y * inv_b - mean.y * mean.y);
    inv.z = 1.0f / sqrtf(Q.z * inv_b - mean.z * mean.z);
    inv.w = 1.0f / sqrtf(Q.w * inv_b - mean.w * mean.w);
    const int c4o = blockIdx.x * 4 + tid;
    reinterpret_cast<float4*>(ws + WS_MEAN)[c4o] = mean;
    reinterpret_cast<float4*>(ws + WS_INVSTD)[c4o] = inv;
  }
}

// ---------------- Pass 2: per-row s, s2 -> |pair_mean|, block partials ----------------
// 4096 blocks, ONE row per wave (va[8] = 32 load VGPRs), launch_bounds(256,8)
// -> 32 waves/CU; LDS 16.4KB x 8 blocks = 131KB fits in 160KB.
constexpr int K3_BLOCKS = 4096;
constexpr int ROWS_PER_BLOCK = B_ROWS / K3_BLOCKS;  // = 4 (1 row per wave)

__global__ __launch_bounds__(256, 8) void rowpass_kernel(
    const float* __restrict__ w, const float* __restrict__ ws,
    float* __restrict__ partials) {
  __shared__ float4 sm_mean[N_COLS / 4];  // 8 KiB
  __shared__ float4 sm_inv[N_COLS / 4];   // 8 KiB
  __shared__ float warpsum[4];

  const float4* __restrict__ g_mean = reinterpret_cast<const float4*>(ws + WS_MEAN);
  const float4* __restrict__ g_inv = reinterpret_cast<const float4*>(ws + WS_INVSTD);
#pragma unroll
  for (int i = 0; i < 2; ++i) {
    const int idx = threadIdx.x + i * 256;
    sm_mean[idx] = g_mean[idx];
    sm_inv[idx] = g_inv[idx];
  }
  __syncthreads();

  const int wid = threadIdx.x >> 6;
  const int lane = threadIdx.x & 63;
  constexpr float inv_pairs = 1.0f / ((float)N_COLS * (float)(N_COLS - 1));

  const int row = blockIdx.x * ROWS_PER_BLOCK + wid;
  const float4* __restrict__ rp =
      reinterpret_cast<const float4*>(w + (size_t)row * N_COLS);

  float4 va[8];
#pragma unroll
  for (int k = 0; k < 8; ++k) va[k] = rp[lane + k * 64];

  float s = 0.f, q = 0.f;
#pragma unroll
  for (int k = 0; k < 8; ++k) {
    const int idx = lane + k * 64;
    float4 m = sm_mean[idx];
    float4 iv = sm_inv[idx];
    float ax = (va[k].x - m.x) * iv.x, ay = (va[k].y - m.y) * iv.y;
    float az = (va[k].z - m.z) * iv.z, aw = (va[k].w - m.w) * iv.w;
    s += (ax + ay) + (az + aw);
    q += fmaf(ax, ax, fmaf(ay, ay, fmaf(az, az, aw * aw)));
  }
#pragma unroll
  for (int off = 32; off > 0; off >>= 1) {
    s += __shfl_xor(s, off);
    q += __shfl_xor(q, off);
  }
  if (lane == 0) {
    float pm = (s * s - q) * inv_pairs;
    warpsum[wid] = fabsf(pm);
  }
  __syncthreads();
  if (threadIdx.x == 0)
    partials[blockIdx.x] = (warpsum[0] + warpsum[1]) + (warpsum[2] + warpsum[3]);
}

// ---------------- Final reduce ----------------
__global__ __launch_bounds__(256) void final_reduce_kernel(
    const float* __restrict__ partials, float* __restrict__ out) {
  __shared__ float warpsum[4];
  float acc = 0.f;
  for (int i = threadIdx.x; i < K3_BLOCKS; i += 256) acc += partials[i];
#pragma unroll
  for (int off = 32; off > 0; off >>= 1) acc += __shfl_xor(acc, off);
  const int wid = threadIdx.x >> 6;
  const int lane = threadIdx.x & 63;
  if (lane == 0) warpsum[wid] = acc;
  __syncthreads();
  if (threadIdx.x == 0) {
    float total = (warpsum[0] + warpsum[1]) + (warpsum[2] + warpsum[3]);
    out[0] = total * (1.0f / (float)B_ROWS);  // L = 1.0
  }
}

extern "C" void kernel_launch(void* const* d_in, const int* in_sizes, int n_in,
                              void* d_out, int out_size, void* d_ws, size_t ws_size,
                              hipStream_t stream) {
  const float* w = reinterpret_cast<const float*>(d_in[0]);
  float* out = reinterpret_cast<float*>(d_out);
  float* ws = reinterpret_cast<float*>(d_ws);

  colstats_kernel<<<K1_ROWCHUNKS * 2, 256, 0, stream>>>(w, ws + WS_PART);
  stats_reduce_kernel<<<128, 256, 0, stream>>>(ws + WS_PART, ws);
  rowpass_kernel<<<K3_BLOCKS, 256, 0, stream>>>(w, ws, ws + WS_RP);
  final_reduce_kernel<<<1, 256, 0, stream>>>(ws + WS_RP, out);
}

// Round 7
// 223.507 us; speedup vs baseline: 1.0007x; 1.0007x over previous
//
#include <hip/hip_runtime.h>
#include <math.h>

// Problem constants (from reference): w is [B, N] float32, L = 1.0
#define B_ROWS 16384
#define N_COLS 2048

// ---- ws layout (floats) ----
// Partials: 2048 blocks x 2048 floats each:
//   as float4: P4[b*512 + tid]       = column-sum of thread tid's column
//              P4[b*512 + 256 + tid] = column-sum-of-squares
// Thread (b,tid)'s column c4 = (b*256+tid) & 511  (grid-stride walk keeps it fixed)
#define WS_PART     0
#define WS_MEAN     (2048 * 2048)                // 2048 floats
#define WS_INVSTD   (WS_MEAN + N_COLS)           // 2048 floats
#define WS_RP       (WS_INVSTD + N_COLS)         // 4096 rowpass block partials
// total ~16.8 MB

// ---------------- Pass 1: column partial sums via UNIT-STRIDE grid sweep ----
// 2048 blocks x 256 threads = 524288 threads = 512 col4 x 1024 rows exactly.
// Load j of the whole grid touches one contiguous 8 MB slab (the pattern that
// measures 6.9 TB/s in fillBuffer / m13 copy), and each thread's float4-column
// (idx & 511) is invariant across the 16 steps -> private accumulation.
constexpr int K1_BLOCKS = 2048;
constexpr size_t NT = (size_t)K1_BLOCKS * 256;          // 524288
constexpr int K1_STEPS = (B_ROWS * N_COLS / 4) / NT;    // = 16

__global__ __launch_bounds__(256, 8) void colstats_kernel(
    const float* __restrict__ w, float* __restrict__ part) {
  const size_t t = (size_t)blockIdx.x * 256 + threadIdx.x;
  const float4* __restrict__ w4 = reinterpret_cast<const float4*>(w);

  float sx = 0.f, sy = 0.f, sz = 0.f, sw = 0.f;
  float qx = 0.f, qy = 0.f, qz = 0.f, qw = 0.f;
#pragma unroll 1
  for (int batch = 0; batch < K1_STEPS / 8; ++batch) {
    float4 v[8];
#pragma unroll
    for (int i = 0; i < 8; ++i)
      v[i] = w4[(size_t)(batch * 8 + i) * NT + t];
#pragma unroll
    for (int i = 0; i < 8; ++i) {
      sx += v[i].x; sy += v[i].y; sz += v[i].z; sw += v[i].w;
      qx = fmaf(v[i].x, v[i].x, qx);
      qy = fmaf(v[i].y, v[i].y, qy);
      qz = fmaf(v[i].z, v[i].z, qz);
      qw = fmaf(v[i].w, v[i].w, qw);
    }
  }
  float4* __restrict__ p4 = reinterpret_cast<float4*>(part);
  p4[(size_t)blockIdx.x * 512 + threadIdx.x] = make_float4(sx, sy, sz, sw);
  p4[(size_t)blockIdx.x * 512 + 256 + threadIdx.x] = make_float4(qx, qy, qz, qw);
}

// ---------------- Fused reduce (2048 block-partials) + finalize mean/invstd ----
// Column c4 = hi*256+lo has partials in blocks b = 2k+hi (k=0..1023) at lane lo.
// Address as float4: P4[k*1024 + hi*512 + sel*256 + lo].
// 128 blocks x 256 threads: c4 = blk*4 + (tid&3); sub = tid>>2 covers 16 k's.
__global__ __launch_bounds__(256) void stats_reduce_kernel(
    const float* __restrict__ part, float* __restrict__ ws) {
  const int tid = threadIdx.x;
  const int c4 = blockIdx.x * 4 + (tid & 3);  // float4 column index [0,512)
  const int hi = c4 >> 8;
  const int lo = c4 & 255;
  const int sub = tid >> 2;                   // 0..63
  const float4* __restrict__ p4 = reinterpret_cast<const float4*>(part);

  float4 s = make_float4(0.f, 0.f, 0.f, 0.f);
  float4 q = make_float4(0.f, 0.f, 0.f, 0.f);
#pragma unroll 1
  for (int i = 0; i < 16; ++i) {
    const int k = sub * 16 + i;
    const size_t base = (size_t)k * 1024 + hi * 512 + lo;
    float4 a = p4[base];
    float4 b = p4[base + 256];
    s.x += a.x; s.y += a.y; s.z += a.z; s.w += a.w;
    q.x += b.x; q.y += b.y; q.z += b.z; q.w += b.w;
  }
  // Reduce over sub bits within the wave (sub bits 0..3 = lane bits 2..5).
#pragma unroll
  for (int off = 4; off <= 32; off <<= 1) {
    s.x += __shfl_xor(s.x, off); s.y += __shfl_xor(s.y, off);
    s.z += __shfl_xor(s.z, off); s.w += __shfl_xor(s.w, off);
    q.x += __shfl_xor(q.x, off); q.y += __shfl_xor(q.y, off);
    q.z += __shfl_xor(q.z, off); q.w += __shfl_xor(q.w, off);
  }
  __shared__ float4 red_s[4][4];  // [wave][c4 residue]
  __shared__ float4 red_q[4][4];
  const int wid = tid >> 6;
  const int lane = tid & 63;
  if (lane < 4) {
    red_s[wid][lane] = s;
    red_q[wid][lane] = q;
  }
  __syncthreads();
  if (tid < 4) {
    float4 S = red_s[0][tid], Q = red_q[0][tid];
#pragma unroll
    for (int w_ = 1; w_ < 4; ++w_) {
      S.x += red_s[w_][tid].x; S.y += red_s[w_][tid].y;
      S.z += red_s[w_][tid].z; S.w += red_s[w_][tid].w;
      Q.x += red_q[w_][tid].x; Q.y += red_q[w_][tid].y;
      Q.z += red_q[w_][tid].z; Q.w += red_q[w_][tid].w;
    }
    const float inv_b = 1.0f / (float)B_ROWS;
    float4 mean, inv;
    mean.x = S.x * inv_b; mean.y = S.y * inv_b;
    mean.z = S.z * inv_b; mean.w = S.w * inv_b;
    inv.x = 1.0f / sqrtf(Q.x * inv_b - mean.x * mean.x);
    inv.y = 1.0f / sqrtf(Q.y * inv_b - mean.y * mean.y);
    inv.z = 1.0f / sqrtf(Q.z * inv_b - mean.z * mean.z);
    inv.w = 1.0f / sqrtf(Q.w * inv_b - mean.w * mean.w);
    const int c4o = blockIdx.x * 4 + tid;
    reinterpret_cast<float4*>(ws + WS_MEAN)[c4o] = mean;
    reinterpret_cast<float4*>(ws + WS_INVSTD)[c4o] = inv;
  }
}

// ---------------- Pass 2: per-row s, s2 -> |pair_mean|, block partials ----------------
// 4096 blocks, ONE row per wave (va[8] = 32 load VGPRs), launch_bounds(256,8)
// -> 32 waves/CU; LDS 16.4KB x 8 blocks = 131KB fits in 160KB.
constexpr int K3_BLOCKS = 4096;
constexpr int ROWS_PER_BLOCK = B_ROWS / K3_BLOCKS;  // = 4 (1 row per wave)

__global__ __launch_bounds__(256, 8) void rowpass_kernel(
    const float* __restrict__ w, const float* __restrict__ ws,
    float* __restrict__ partials) {
  __shared__ float4 sm_mean[N_COLS / 4];  // 8 KiB
  __shared__ float4 sm_inv[N_COLS / 4];   // 8 KiB
  __shared__ float warpsum[4];

  const float4* __restrict__ g_mean = reinterpret_cast<const float4*>(ws + WS_MEAN);
  const float4* __restrict__ g_inv = reinterpret_cast<const float4*>(ws + WS_INVSTD);
#pragma unroll
  for (int i = 0; i < 2; ++i) {
    const int idx = threadIdx.x + i * 256;
    sm_mean[idx] = g_mean[idx];
    sm_inv[idx] = g_inv[idx];
  }
  __syncthreads();

  const int wid = threadIdx.x >> 6;
  const int lane = threadIdx.x & 63;
  constexpr float inv_pairs = 1.0f / ((float)N_COLS * (float)(N_COLS - 1));

  const int row = blockIdx.x * ROWS_PER_BLOCK + wid;
  const float4* __restrict__ rp =
      reinterpret_cast<const float4*>(w + (size_t)row * N_COLS);

  float4 va[8];
#pragma unroll
  for (int k = 0; k < 8; ++k) va[k] = rp[lane + k * 64];

  float s = 0.f, q = 0.f;
#pragma unroll
  for (int k = 0; k < 8; ++k) {
    const int idx = lane + k * 64;
    float4 m = sm_mean[idx];
    float4 iv = sm_inv[idx];
    float ax = (va[k].x - m.x) * iv.x, ay = (va[k].y - m.y) * iv.y;
    float az = (va[k].z - m.z) * iv.z, aw = (va[k].w - m.w) * iv.w;
    s += (ax + ay) + (az + aw);
    q += fmaf(ax, ax, fmaf(ay, ay, fmaf(az, az, aw * aw)));
  }
#pragma unroll
  for (int off = 32; off > 0; off >>= 1) {
    s += __shfl_xor(s, off);
    q += __shfl_xor(q, off);
  }
  if (lane == 0) {
    float pm = (s * s - q) * inv_pairs;
    warpsum[wid] = fabsf(pm);
  }
  __syncthreads();
  if (threadIdx.x == 0)
    partials[blockIdx.x] = (warpsum[0] + warpsum[1]) + (warpsum[2] + warpsum[3]);
}

// ---------------- Final reduce ----------------
__global__ __launch_bounds__(256) void final_reduce_kernel(
    const float* __restrict__ partials, float* __restrict__ out) {
  __shared__ float warpsum[4];
  float acc = 0.f;
  for (int i = threadIdx.x; i < K3_BLOCKS; i += 256) acc += partials[i];
#pragma unroll
  for (int off = 32; off > 0; off >>= 1) acc += __shfl_xor(acc, off);
  const int wid = threadIdx.x >> 6;
  const int lane = threadIdx.x & 63;
  if (lane == 0) warpsum[wid] = acc;
  __syncthreads();
  if (threadIdx.x == 0) {
    float total = (warpsum[0] + warpsum[1]) + (warpsum[2] + warpsum[3]);
    out[0] = total * (1.0f / (float)B_ROWS);  // L = 1.0
  }
}

extern "C" void kernel_launch(void* const* d_in, const int* in_sizes, int n_in,
                              void* d_out, int out_size, void* d_ws, size_t ws_size,
                              hipStream_t stream) {
  const float* w = reinterpret_cast<const float*>(d_in[0]);
  float* out = reinterpret_cast<float*>(d_out);
  float* ws = reinterpret_cast<float*>(d_ws);

  colstats_kernel<<<K1_BLOCKS, 256, 0, stream>>>(w, ws + WS_PART);
  stats_reduce_kernel<<<128, 256, 0, stream>>>(ws + WS_PART, ws);
  rowpass_kernel<<<K3_BLOCKS, 256, 0, stream>>>(w, ws, ws + WS_RP);
  final_reduce_kernel<<<1, 256, 0, stream>>>(ws + WS_RP, out);
}